// Round 12
// baseline (629.556 us; speedup 1.0000x reference)
//
#include <hip/hip_runtime.h>

typedef __attribute__((ext_vector_type(4))) float f32x4;
typedef __attribute__((ext_vector_type(8))) short bf16x8;
typedef __attribute__((ext_vector_type(4))) unsigned int uint4v;
typedef __attribute__((ext_vector_type(4))) unsigned short ushort4v;
typedef unsigned short u16;
typedef unsigned int u32;

#define AS1(p) ((const __attribute__((address_space(1))) u32*)(p))
#define AS3(p) ((__attribute__((address_space(3))) u32*)(p))

__device__ __forceinline__ float bf2f(u16 v) {
    u32 u = ((u32)v) << 16;
    return __builtin_bit_cast(float, u);
}
__device__ __forceinline__ u16 f2bf(float f) {
    u32 u = __builtin_bit_cast(u32, f);
    u += 0x7fffu + ((u >> 16) & 1u);   // RNE
    return (u16)(u >> 16);
}

// ---------------------------------------------------------------- convert x
__global__ __launch_bounds__(256) void k_cvt_bf16(const float* __restrict__ in,
                                                  u16* __restrict__ out, int n8) {
    int t = blockIdx.x * 256 + threadIdx.x;
    if (t >= n8) return;
    const f32x4* p = (const f32x4*)in + (size_t)t * 2;
    f32x4 a = p[0], b = p[1];
    uint4v o;
    o[0] = (u32)f2bf(a[0]) | ((u32)f2bf(a[1]) << 16);
    o[1] = (u32)f2bf(a[2]) | ((u32)f2bf(a[3]) << 16);
    o[2] = (u32)f2bf(b[0]) | ((u32)f2bf(b[1]) << 16);
    o[3] = (u32)f2bf(b[2]) | ((u32)f2bf(b[3]) << 16);
    *((uint4v*)(out + (size_t)t * 8)) = o;
}

// ------------------------------------------- transpose-convert W -> W^T bf16
__global__ __launch_bounds__(256) void k_transpose_bf16(const float* __restrict__ in,
                                                        u16* __restrict__ out,
                                                        int R, int C) {
    __shared__ float tile[32][33];
    const int bx = blockIdx.x * 32, by = blockIdx.y * 32;
    const int tx = threadIdx.x & 31, ty = threadIdx.x >> 5;   // 256 threads
#pragma unroll
    for (int i = 0; i < 32; i += 8)
        tile[ty + i][tx] = in[(size_t)(by + ty + i) * C + bx + tx];
    __syncthreads();
#pragma unroll
    for (int i = 0; i < 32; i += 8)
        out[(size_t)(bx + ty + i) * R + by + tx] = f2bf(tile[tx][ty + i]);
}

// ===================================================== GEMM  C = A*B^T + b
// 128x256 tile, BK=32, 8 waves (2x4), 16x16x32 MFMA, 2-deep LDS ring at
// 2 BLOCKS/CU (LDS 48 KB, VGPR ~120 <= 128 via launch_bounds(512,4)):
// cross-block overlap hides barrier/latency stalls a single resident
// block exposes (the r5-r9 235us plateau at MfmaUtil 37%).
// One barrier per K-step: reads of buf[t] complete (lgkm before MFMA)
// before the barrier; STAGE(t+2) (overwriting buf[t]) issues only after it.
// Frag-major pages (1 KB, lane l at l*16B): conflict-free, linear gload dst.
// 1D grid + bijective XCD swizzle: each XCD owns nbcol/8 B-panels (L2-res).
template <int OUT_BF16>
__global__ __launch_bounds__(512, 4) void k_gemm128(const u16* __restrict__ A,
                                                    const u16* __restrict__ Bt,
                                                    const float* __restrict__ bias,
                                                    void* __restrict__ Cout,
                                                    int M, int N, int K) {
    __shared__ u16 lds[24576];           // A: [2][4096] u16 at 0; B: [2][8192] at 8192
    const int tid = threadIdx.x;
    const int wid = tid >> 6, l = tid & 63;
    const int lr = l & 15, lg = l >> 4;
    const int wm = wid >> 2, wn = wid & 3;          // 2 x 4 wave grid, out 64x64/wave
    const int nbrow = M >> 7;                        // M/128
    const int nbcol = N >> 8;                        // N/256 (multiple of 8)
    const int xcd = blockIdx.x & 7, id2 = blockIdx.x >> 3;
    const int colPerXcd = nbcol >> 3;
    const size_t brow = (size_t)(id2 % nbrow) * 128;
    const size_t bcol = (size_t)(xcd * colPerXcd + id2 / nbrow) * 256;
    const int KT = K >> 5;

    // staging: wave stages A page wid, B pages wid and wid+8 (1 gload each)
    const u16* gA  = A  + (brow + (size_t)wid * 16 + lr) * K + lg * 8;
    const u16* gB0 = Bt + (bcol + (size_t)wid * 16 + lr) * K + lg * 8;
    const u16* gB1 = Bt + (bcol + (size_t)(wid + 8) * 16 + lr) * K + lg * 8;

    f32x4 acc[4][4];
#pragma unroll
    for (int m = 0; m < 4; ++m)
#pragma unroll
        for (int n = 0; n < 4; ++n) acc[m][n] = (f32x4){0.f, 0.f, 0.f, 0.f};

#define STAGE(t)                                                                                     \
    do {                                                                                             \
        const int b_ = (t) & 1;                                                                      \
        const int k0_ = (t) << 5;                                                                    \
        __builtin_amdgcn_global_load_lds(AS1(gA + k0_),  AS3(&lds[b_ * 4096 + wid * 512]), 16, 0, 0);\
        __builtin_amdgcn_global_load_lds(AS1(gB0 + k0_), AS3(&lds[8192 + b_ * 8192 + wid * 512]), 16, 0, 0); \
        __builtin_amdgcn_global_load_lds(AS1(gB1 + k0_), AS3(&lds[8192 + b_ * 8192 + (wid + 8) * 512]), 16, 0, 0); \
    } while (0)

    STAGE(0);
    asm volatile("s_waitcnt vmcnt(0)" ::: "memory");
    __builtin_amdgcn_s_barrier();
    __builtin_amdgcn_sched_barrier(0);

#pragma unroll 1
    for (int t = 0; t < KT; ++t) {
        if (t + 1 < KT) STAGE(t + 1);
        const u16* pa = &lds[(t & 1) * 4096 + (wm * 4) * 512 + l * 8];
        const u16* pb = &lds[8192 + (t & 1) * 8192 + (wn * 4) * 512 + l * 8];
        bf16x8 af[4], bfr[4];
#pragma unroll
        for (int m = 0; m < 4; ++m) af[m] = *(const bf16x8*)(pa + m * 512);
#pragma unroll
        for (int n = 0; n < 4; ++n) bfr[n] = *(const bf16x8*)(pb + n * 512);
        __builtin_amdgcn_s_setprio(1);
#pragma unroll
        for (int m = 0; m < 4; ++m)
#pragma unroll
            for (int n = 0; n < 4; ++n)
                acc[m][n] = __builtin_amdgcn_mfma_f32_16x16x32_bf16(af[m], bfr[n], acc[m][n], 0, 0, 0);
        __builtin_amdgcn_s_setprio(0);
        __builtin_amdgcn_sched_barrier(0);
        if (t + 1 < KT) asm volatile("s_waitcnt vmcnt(0)" ::: "memory");
        __builtin_amdgcn_s_barrier();
        __builtin_amdgcn_sched_barrier(0);
    }
#undef STAGE

    // epilogue (16x16 C/D layout: col=lane&15, row=(lane>>4)*4+reg)
#pragma unroll
    for (int m = 0; m < 4; ++m) {
        const size_t row0 = brow + wm * 64 + m * 16 + lg * 4;
#pragma unroll
        for (int n = 0; n < 4; ++n) {
            const size_t col = bcol + wn * 64 + n * 16 + lr;
            const float bv = bias[col];
#pragma unroll
            for (int r = 0; r < 4; ++r) {
                float v = acc[m][n][r] + bv;
                if (OUT_BF16)
                    ((u16*)Cout)[(row0 + r) * N + col] = f2bf(v);
                else
                    ((float*)Cout)[(row0 + r) * N + col] = v;
            }
        }
    }
}

// ------------------------------------------------------------------- RoPE
__global__ __launch_bounds__(256) void k_rope(const u16* __restrict__ qkv,
                                              const float* __restrict__ fcos,
                                              const float* __restrict__ fsin,
                                              u16* __restrict__ qb, u16* __restrict__ kb) {
    const int t = blockIdx.x * 256 + threadIdx.x;
    const int e = t & 7, h = (t >> 3) & 15, r = (t >> 7) & 1, s = (t >> 8) & 2047, b = t >> 19;
    const u16* src = qkv + ((size_t)(b * 2048 + s)) * 6144 + r * 2048 + h * 128 + e * 16;
    uint4v p0 = *(const uint4v*)src;
    uint4v p1 = *(const uint4v*)(src + 8);
    const float* cp = fcos + s * 64 + e * 8;
    const float* sp = fsin + s * 64 + e * 8;
    f32x4 c0 = *(const f32x4*)cp, c1 = *(const f32x4*)(cp + 4);
    f32x4 s0 = *(const f32x4*)sp, s1 = *(const f32x4*)(sp + 4);
    float x[16];
#pragma unroll
    for (int i = 0; i < 4; ++i) {
        x[2 * i]     = bf2f((u16)(p0[i] & 0xffff));
        x[2 * i + 1] = bf2f((u16)(p0[i] >> 16));
        x[8 + 2 * i]     = bf2f((u16)(p1[i] & 0xffff));
        x[8 + 2 * i + 1] = bf2f((u16)(p1[i] >> 16));
    }
    float c[8]  = {c0[0], c0[1], c0[2], c0[3], c1[0], c1[1], c1[2], c1[3]};
    float sn[8] = {s0[0], s0[1], s0[2], s0[3], s1[0], s1[1], s1[2], s1[3]};
    u32 ow[8];
#pragma unroll
    for (int i = 0; i < 8; ++i) {
        float xr = x[2 * i], xi = x[2 * i + 1];
        float orr = xr * c[i] - xi * sn[i];
        float oii = xr * sn[i] + xi * c[i];
        ow[i] = (u32)f2bf(orr) | ((u32)f2bf(oii) << 16);
    }
    u16* dst = (r ? kb : qb) + ((size_t)((b * 16 + h) * 2048 + s)) * 128 + e * 16;
    uint4v q0 = {ow[0], ow[1], ow[2], ow[3]};
    uint4v q1 = {ow[4], ow[5], ow[6], ow[7]};
    *(uint4v*)dst = q0;
    *(uint4v*)(dst + 8) = q1;
}

// ------------------------------------------------- causal flash attention
// Swapped QK^T (mfma(K,Q)): lane holds 16 P-values of ONE q-row (col=lane&15)
// -> row max/sum are in-lane + 2 butterflies. Counted vmcnt, raw barriers,
// paired q-tiles (x,15-x), XCD-local mapping.
struct VtRegs { uint4v v0, v1, v2, v3; };

__device__ __forceinline__ void attn_stage_k(const u16* kp, int kbase, u16* dstBase,
                                             int w, int lr, int lg) {
#pragma unroll
    for (int c = 0; c < 4; ++c) {
        const int row = w * 16 + c * 4 + lg;
        const int sslot = lr ^ (4 * (c & 1) + lg);           // inverse swizzle on source
        const u16* gsrc = kp + (size_t)(kbase + row) * 128 + sslot * 8;
        __builtin_amdgcn_global_load_lds(AS1(gsrc), AS3(dstBase + (w * 16 + c * 4) * 128), 16, 0, 0);
    }
}

__device__ __forceinline__ VtRegs attn_load_v(const u16* vp, int kbase, int tid) {
    const int rg = tid >> 4, cg = tid & 15;
    const u16* gv = vp + (size_t)(kbase + rg * 4) * 6144 + cg * 8;
    VtRegs r;
    r.v0 = *(const uint4v*)gv;
    r.v1 = *(const uint4v*)(gv + 6144);
    r.v2 = *(const uint4v*)(gv + 2 * 6144);
    r.v3 = *(const uint4v*)(gv + 3 * 6144);
    return r;
}

__device__ __forceinline__ void attn_write_v(u16 (*Vt)[64], const VtRegs& r, int tid) {
    const int rg = tid >> 4, cg = tid & 15;
    const u16* u0 = (const u16*)&r.v0;
    const u16* u1 = (const u16*)&r.v1;
    const u16* u2 = (const u16*)&r.v2;
    const u16* u3 = (const u16*)&r.v3;
    const int sb = rg >> 1, hf = (rg & 1) * 4;
#pragma unroll
    for (int cc = 0; cc < 8; ++cc) {
        const int row = cg * 8 + cc;                          // hd index
        const int col = ((sb ^ ((cg ^ cc) & 7)) << 3) + hf;   // swizzled seq slot
        ushort4v pk = {u0[cc], u1[cc], u2[cc], u3[cc]};
        *(ushort4v*)&Vt[row][col] = pk;
    }
}

__device__ __forceinline__ void attn_qtile(int qt, const u16* qp, const u16* kp,
                                           const u16* vp, u16* yp,
                                           u16 (*Ks)[64][128], u16 (*Vt)[64],
                                           u16 (*Psw)[72],
                                           int w, int lr, int lg, int tid) {
    const int qw = qt * 128 + w * 32;
    const int l = tid & 63;

    bf16x8 qf[2][4];
#pragma unroll
    for (int i = 0; i < 2; ++i)
#pragma unroll
        for (int ks = 0; ks < 4; ++ks)
            qf[i][ks] = *(const bf16x8*)(qp + (size_t)(qw + i * 16 + lr) * 128 + ks * 32 + lg * 8);

    f32x4 acc[2][8];
#pragma unroll
    for (int i = 0; i < 2; ++i)
#pragma unroll
        for (int j = 0; j < 8; ++j) acc[i][j] = (f32x4){0.f, 0.f, 0.f, 0.f};
    float mrow[2] = {-1e30f, -1e30f}, lrow[2] = {0.f, 0.f};   // for q-row = mt*16+lr

    const float scale = 0.08838834764831845f;   // 1/sqrt(128)
    const int nkt = 2 * qt + 2;

    // ---- prologue: V loads first, then K stage (vmcnt(4) leaves K in flight)
    VtRegs vr = attn_load_v(vp, 0, tid);
    attn_stage_k(kp, 0, &Ks[0][0][0], w, lr, lg);
    attn_write_v(Vt, vr, tid);
    __syncthreads();

    int cur = 0;
    for (int kt = 0; kt < nkt; ++kt) {
        const int kbase = kt * 64;
        const bool pf = (kt + 1 < nkt);
        if (pf) {                       // V loads BEFORE K stage (oldest-first drain)
            vr = attn_load_v(vp, kbase + 64, tid);
            attn_stage_k(kp, kbase + 64, &Ks[cur ^ 1][0][0], w, lr, lg);
        }

        if (kbase <= qw + 31) {
            // ---- S^T = K Q^T (swapped operands): lane holds q=mt*16+lr (col),
            //      kv = nt*16 + lg*4 + r (row) -> reduction axis is in-lane!
            f32x4 st[2][4];
#pragma unroll
            for (int i = 0; i < 2; ++i)
#pragma unroll
                for (int j = 0; j < 4; ++j) st[i][j] = (f32x4){0.f, 0.f, 0.f, 0.f};
#pragma unroll
            for (int nt = 0; nt < 4; ++nt) {
#pragma unroll
                for (int ks = 0; ks < 4; ++ks) {
                    const int slot = (ks * 4 + lg) ^ (lr & 7);
                    bf16x8 kf = *(const bf16x8*)&Ks[cur][nt * 16 + lr][slot * 8];
#pragma unroll
                    for (int mt = 0; mt < 2; ++mt)
                        st[mt][nt] = __builtin_amdgcn_mfma_f32_16x16x32_bf16(kf, qf[mt][ks], st[mt][nt], 0, 0, 0);
                }
            }
            // ---- scale + causal mask (ki rows, qi cols)
            const bool pm = (kbase + 63 > qw);
#pragma unroll
            for (int mt = 0; mt < 2; ++mt)
#pragma unroll
                for (int nt = 0; nt < 4; ++nt)
#pragma unroll
                    for (int r = 0; r < 4; ++r) {
                        float v = st[mt][nt][r] * scale;
                        if (pm) {
                            const int qi = qw + mt * 16 + lr;
                            const int ki = kbase + nt * 16 + lg * 4 + r;
                            if (ki > qi) v = -1e30f;
                        }
                        st[mt][nt][r] = v;
                    }
            // ---- row max: 15 in-lane fmax + 2 butterflies across lg copies
            float rm[2], fac[2];
#pragma unroll
            for (int mt = 0; mt < 2; ++mt) {
                float m0 = st[mt][0][0];
#pragma unroll
                for (int nt = 0; nt < 4; ++nt)
#pragma unroll
                    for (int r = 0; r < 4; ++r) m0 = fmaxf(m0, st[mt][nt][r]);
                m0 = fmaxf(m0, __shfl_xor(m0, 16));
                m0 = fmaxf(m0, __shfl_xor(m0, 32));
                rm[mt] = m0;
                const float mn = fmaxf(mrow[mt], m0);
                fac[mt] = __expf(mrow[mt] - mn);
                mrow[mt] = mn;
                lrow[mt] *= fac[mt];
            }
            // ---- redistribute fac to acc layout (acc q-row = lg*4+r)
            float facr[2][4];
#pragma unroll
            for (int mt = 0; mt < 2; ++mt)
#pragma unroll
                for (int r = 0; r < 4; ++r)
                    facr[mt][r] = __shfl(fac[mt], (l & 48) | (lg * 4 + r));
#pragma unroll
            for (int mt = 0; mt < 2; ++mt)
#pragma unroll
                for (int nt = 0; nt < 8; ++nt)
#pragma unroll
                    for (int r = 0; r < 4; ++r) acc[mt][nt][r] *= facr[mt][r];
            // ---- P = exp(S - m): in-lane sum + 2 butterflies
#pragma unroll
            for (int mt = 0; mt < 2; ++mt) {
                float rs = 0.f;
#pragma unroll
                for (int nt = 0; nt < 4; ++nt)
#pragma unroll
                    for (int r = 0; r < 4; ++r) {
                        const float p = __expf(st[mt][nt][r] - mrow[mt]);
                        st[mt][nt][r] = p;
                        rs += p;
                    }
                rs += __shfl_xor(rs, 16);
                rs += __shfl_xor(rs, 32);
                lrow[mt] += rs;
            }
            // ---- P -> LDS, packed b32 (row = q, col = kv)
#pragma unroll
            for (int mt = 0; mt < 2; ++mt)
#pragma unroll
                for (int nt = 0; nt < 4; ++nt) {
                    const u32 p01 = (u32)f2bf(st[mt][nt][0]) | ((u32)f2bf(st[mt][nt][1]) << 16);
                    const u32 p23 = (u32)f2bf(st[mt][nt][2]) | ((u32)f2bf(st[mt][nt][3]) << 16);
                    u16* dst = &Psw[mt * 16 + lr][nt * 16 + lg * 4];
                    *(u32*)dst = p01;
                    *(u32*)(dst + 2) = p23;
                }
            // ---- PV
#pragma unroll
            for (int k2 = 0; k2 < 2; ++k2) {
                bf16x8 pa[2];
                pa[0] = *(const bf16x8*)&Psw[lr][k2 * 32 + lg * 8];
                pa[1] = *(const bf16x8*)&Psw[16 + lr][k2 * 32 + lg * 8];
#pragma unroll
                for (int nt = 0; nt < 8; ++nt) {
                    const int f = ((nt * 2 + (lr >> 3)) ^ lr) & 7;
                    const int slot = (k2 * 4 + lg) ^ f;
                    bf16x8 vb = *(const bf16x8*)&Vt[nt * 16 + lr][slot * 8];
#pragma unroll
                    for (int mt = 0; mt < 2; ++mt)
                        acc[mt][nt] = __builtin_amdgcn_mfma_f32_16x16x32_bf16(pa[mt], vb, acc[mt][nt], 0, 0, 0);
                }
            }
        }

        __builtin_amdgcn_s_barrier();          // all waves done reading Ks[cur]/Vt
        __builtin_amdgcn_sched_barrier(0);
        if (pf) {
            asm volatile("s_waitcnt vmcnt(4)" ::: "memory");   // V landed, K still flying
            attn_write_v(Vt, vr, tid);
            asm volatile("s_waitcnt vmcnt(0) lgkmcnt(0)" ::: "memory"); // K in LDS, V writes done
        } else {
            asm volatile("s_waitcnt vmcnt(0) lgkmcnt(0)" ::: "memory");
        }
        __builtin_amdgcn_s_barrier();
        __builtin_amdgcn_sched_barrier(0);
        cur ^= 1;
    }

    // ---- epilogue: y = acc / l (lrow held at lane lr = q-row; redistribute)
#pragma unroll
    for (int mt = 0; mt < 2; ++mt)
#pragma unroll
        for (int r = 0; r < 4; ++r) {
            const float lsum = __shfl(lrow[mt], (l & 48) | (lg * 4 + r));
            const float inv = 1.f / lsum;
            const size_t row = qw + mt * 16 + lg * 4 + r;
#pragma unroll
            for (int nt = 0; nt < 8; ++nt)
                yp[row * 2048 + nt * 16 + lr] = f2bf(acc[mt][nt][r] * inv);
        }
}

__global__ __launch_bounds__(256, 2) void k_attn(const u16* __restrict__ qb,
                                                 const u16* __restrict__ kb,
                                                 const u16* __restrict__ qkv,
                                                 u16* __restrict__ yb) {
    __shared__ u16 Ks[2][64][128];   // double-buffered, swizzled 16B slots
    __shared__ u16 Vt[128][64];      // V^T, swizzled
    __shared__ u16 Ps[4][32][72];    // per-wave P, padded

    const int gid = blockIdx.x;
    const int x = gid >> 6;          // pair index 0..7 -> q-tiles (x, 15-x)
    const int g = gid & 63;          // (b,h) group; gid%8 == g%8 -> same XCD
    const int h = g & 15, b = g >> 4;
    const int tid = threadIdx.x;
    const int w = tid >> 6, l = tid & 63;
    const int lr = l & 15, lg = l >> 4;

    const u16* qp = qb + (size_t)((b * 16 + h) * 2048) * 128;
    const u16* kp = kb + (size_t)((b * 16 + h) * 2048) * 128;
    const u16* vp = qkv + (size_t)(b * 2048) * 6144 + 4096 + h * 128;
    u16* yp = yb + (size_t)(b * 2048) * 2048 + h * 128;

    attn_qtile(x,      qp, kp, vp, yp, Ks, Vt, Ps[w], w, lr, lg, tid);
    attn_qtile(15 - x, qp, kp, vp, yp, Ks, Vt, Ps[w], w, lr, lg, tid);
}

// --------------------------------------------------------------------------
extern "C" void kernel_launch(void* const* d_in, const int* in_sizes, int n_in,
                              void* d_out, int out_size, void* d_ws, size_t ws_size,
                              hipStream_t stream) {
    const float* x    = (const float*)d_in[0];
    const float* fcos = (const float*)d_in[1];
    const float* fsin = (const float*)d_in[2];
    const float* Wqkv = (const float*)d_in[3];
    const float* bqkv = (const float*)d_in[4];
    const float* Wout = (const float*)d_in[5];
    const float* bout = (const float*)d_in[6];
    float* out = (float*)d_out;

    if (ws_size < 234881024u) return;   // need 224 MB scratch

    char* ws = (char*)d_ws;
    u16* x_bf  = (u16*)(ws);                 // 32 MB  (aliased later by yb)
    u16* wqkvT = (u16*)(ws + 33554432);      // 24 MB
    u16* woutT = (u16*)(ws + 58720256);      //  8 MB
    u16* qkv   = (u16*)(ws + 67108864);      // 96 MB (q,k,v bf16; v read in-place)
    u16* qb    = (u16*)(ws + 167772160);     // 32 MB
    u16* kb    = (u16*)(ws + 201326592);     // 32 MB
    u16* yb    = x_bf;                       // alias: x_bf dead after GEMM1

    k_cvt_bf16<<<8192, 256, 0, stream>>>(x, x_bf, 2097152);
    k_transpose_bf16<<<dim3(192, 64), 256, 0, stream>>>(Wqkv, wqkvT, 2048, 6144);
    k_transpose_bf16<<<dim3(64, 64), 256, 0, stream>>>(Wout, woutT, 2048, 2048);
    k_gemm128<1><<<1536, 512, 0, stream>>>(x_bf, wqkvT, bqkv, qkv, 8192, 6144, 2048);
    k_rope<<<8192, 256, 0, stream>>>(qkv, fcos, fsin, qb, kb);
    k_attn<<<512, 256, 0, stream>>>(qb, kb, qkv, yb);
    k_gemm128<0><<<512, 512, 0, stream>>>(yb, woutT, bout, out, 8192, 2048, 2048);
}

// Round 13
// 515.801 us; speedup vs baseline: 1.2205x; 1.2205x over previous
//
#include <hip/hip_runtime.h>

typedef __attribute__((ext_vector_type(4))) float f32x4;
typedef __attribute__((ext_vector_type(8))) short bf16x8;
typedef __attribute__((ext_vector_type(4))) unsigned int uint4v;
typedef __attribute__((ext_vector_type(4))) unsigned short ushort4v;
typedef unsigned short u16;
typedef unsigned int u32;

#define AS1(p) ((const __attribute__((address_space(1))) u32*)(p))
#define AS3(p) ((__attribute__((address_space(3))) u32*)(p))

__device__ __forceinline__ float bf2f(u16 v) {
    u32 u = ((u32)v) << 16;
    return __builtin_bit_cast(float, u);
}
__device__ __forceinline__ u16 f2bf(float f) {
    u32 u = __builtin_bit_cast(u32, f);
    u += 0x7fffu + ((u >> 16) & 1u);   // RNE
    return (u16)(u >> 16);
}

// ---------------------------------------------------------------- convert x
__global__ __launch_bounds__(256) void k_cvt_bf16(const float* __restrict__ in,
                                                  u16* __restrict__ out, int n8) {
    int t = blockIdx.x * 256 + threadIdx.x;
    if (t >= n8) return;
    const f32x4* p = (const f32x4*)in + (size_t)t * 2;
    f32x4 a = p[0], b = p[1];
    uint4v o;
    o[0] = (u32)f2bf(a[0]) | ((u32)f2bf(a[1]) << 16);
    o[1] = (u32)f2bf(a[2]) | ((u32)f2bf(a[3]) << 16);
    o[2] = (u32)f2bf(b[0]) | ((u32)f2bf(b[1]) << 16);
    o[3] = (u32)f2bf(b[2]) | ((u32)f2bf(b[3]) << 16);
    *((uint4v*)(out + (size_t)t * 8)) = o;
}

// ------------------------------------------- transpose-convert W -> W^T bf16
__global__ __launch_bounds__(256) void k_transpose_bf16(const float* __restrict__ in,
                                                        u16* __restrict__ out,
                                                        int R, int C) {
    __shared__ float tile[32][33];
    const int bx = blockIdx.x * 32, by = blockIdx.y * 32;
    const int tx = threadIdx.x & 31, ty = threadIdx.x >> 5;   // 256 threads
#pragma unroll
    for (int i = 0; i < 32; i += 8)
        tile[ty + i][tx] = in[(size_t)(by + ty + i) * C + bx + tx];
    __syncthreads();
#pragma unroll
    for (int i = 0; i < 32; i += 8)
        out[(size_t)(bx + ty + i) * R + by + tx] = f2bf(tile[tx][ty + i]);
}

// ===================================================== GEMM  C = A*B^T + b
// 256x256 tile, BK=64, 8 waves (2x4), 16x16x32 MFMA, m201-style 8-phase
// schedule (2 K-tiles per iteration) -- the r9 known-good 235us kernel.
// MODE 0: plain f32 output (GEMM2).
// MODE 2: fused RoPE epilogue for the qkv GEMM: q/k tiles rope'd via one
//   __shfl_xor(v,1) pair-exchange and written head-major to qb/kb; v tiles
//   written bf16 to qkv. Region is uniform per block (2048 % 256 == 0).
template <int MODE>
__global__ __launch_bounds__(512, 1) void k_gemm256(const u16* __restrict__ A,
                                                    const u16* __restrict__ Bt,
                                                    const float* __restrict__ bias,
                                                    void* __restrict__ Cout,
                                                    int M, int N, int K,
                                                    const float* __restrict__ fcos,
                                                    const float* __restrict__ fsin,
                                                    u16* __restrict__ qb,
                                                    u16* __restrict__ kb) {
    __shared__ u16 lds[65536];           // A: slots at 0,16384; B at 32768,49152 (u16)
    const int tid = threadIdx.x;
    const int wid = tid >> 6, l = tid & 63;
    const int lr = l & 15, lg = l >> 4;
    const int wm = wid >> 2, wn = wid & 3;          // 2 x 4 wave grid
    const size_t brow = (size_t)blockIdx.x * 256;
    const size_t bcol = (size_t)blockIdx.y * 256;
    const int KT = K >> 6;                           // BK=64 tiles (even, >=4)
    const int NJ = KT >> 1;

    const u16* gArow = A + brow * K;
    const u16* gBrow = Bt + bcol * K;
    const size_t laneoff = (size_t)lr * K + lg * 8;
    // group staged by this wave for each quarter-set
    const int gA1 = (wid & 3) | ((wid & 4) << 1);   // {0,1,2,3,8,9,10,11}
    const int gA2 = gA1 + 4;                        // {4,5,6,7,12,13,14,15}
    const int gB1 = (wid & 1) | ((wid & 6) << 1);   // {0,1,4,5,8,9,12,13}
    const int gB2 = gB1 + 2;                        // {2,3,6,7,10,11,14,15}

    // stage one quarter-set: group g of tile tt (2 gloads: kh=0,1)
    auto STG = [&](const u16* gbase, int opBase, int g, int tt) {
        u16* dst = &lds[opBase + ((tt) & 1) * 16384 + g * 1024];
        const u16* src = gbase + (size_t)g * 16 * K + (size_t)tt * 64 + laneoff;
        __builtin_amdgcn_global_load_lds(AS1(src), AS3(dst), 16, 0, 0);
        __builtin_amdgcn_global_load_lds(AS1(src + 32), AS3(dst + 512), 16, 0, 0);
    };
    auto LDA_ = [&](int slot, int m, int ks) {
        return *(const bf16x8*)&lds[slot * 16384 + ((wm * 8 + m) * 2 + ks) * 512 + l * 8];
    };
    auto LDB_ = [&](int slot, int n, int ks) {
        return *(const bf16x8*)&lds[32768 + slot * 16384 + ((wn * 4 + n) * 2 + ks) * 512 + l * 8];
    };

    f32x4 acc[8][4];
#pragma unroll
    for (int m = 0; m < 8; ++m)
#pragma unroll
        for (int n = 0; n < 4; ++n) acc[m][n] = (f32x4){0.f, 0.f, 0.f, 0.f};

    // ---- prologue: tile0 fully, tile1 all but B2 (B2 staged at iter0 P0)
    STG(gArow, 0, gA1, 0); STG(gBrow, 32768, gB1, 0);
    STG(gArow, 0, gA2, 0); STG(gBrow, 32768, gB2, 0);
    STG(gArow, 0, gA1, 1); STG(gBrow, 32768, gB1, 1);
    STG(gArow, 0, gA2, 1);
    asm volatile("s_waitcnt vmcnt(6)" ::: "memory");   // tile0 landed
    __builtin_amdgcn_s_barrier();

#define OPEN_PHASE()                                              \
    __builtin_amdgcn_s_barrier();                                 \
    asm volatile("s_waitcnt lgkmcnt(0)" ::: "memory");            \
    __builtin_amdgcn_sched_barrier(0);                            \
    __builtin_amdgcn_s_setprio(1);
#define CLOSE_PHASE()                                             \
    __builtin_amdgcn_s_setprio(0);                                \
    __builtin_amdgcn_sched_barrier(0);                            \
    __builtin_amdgcn_s_barrier();

#pragma unroll 1
    for (int j = 0; j < NJ; ++j) {
        const int t0 = 2 * j, t1 = 2 * j + 1;
        const bool pf = (j + 1 < NJ);
        bf16x8 a[4][2], b0[2][2], b1[2][2];

        // ---- P0: t0 Q(m0-3 x n0-1); stage B2(t1)
#pragma unroll
        for (int m = 0; m < 4; ++m)
#pragma unroll
            for (int ks = 0; ks < 2; ++ks) a[m][ks] = LDA_(0, m, ks);
#pragma unroll
        for (int n = 0; n < 2; ++n)
#pragma unroll
            for (int ks = 0; ks < 2; ++ks) b0[n][ks] = LDB_(0, n, ks);
        STG(gBrow, 32768, gB2, t1);
        OPEN_PHASE();
#pragma unroll
        for (int m = 0; m < 4; ++m)
#pragma unroll
            for (int n = 0; n < 2; ++n)
#pragma unroll
                for (int ks = 0; ks < 2; ++ks)
                    acc[m][n] = __builtin_amdgcn_mfma_f32_16x16x32_bf16(a[m][ks], b0[n][ks], acc[m][n], 0, 0, 0);
        CLOSE_PHASE();

        // ---- P1: t0 Q(m0-3 x n2-3); stage A1(t0+2)
#pragma unroll
        for (int n = 0; n < 2; ++n)
#pragma unroll
            for (int ks = 0; ks < 2; ++ks) b1[n][ks] = LDB_(0, n + 2, ks);
        if (pf) STG(gArow, 0, gA1, t0 + 2);
        OPEN_PHASE();
#pragma unroll
        for (int m = 0; m < 4; ++m)
#pragma unroll
            for (int n = 0; n < 2; ++n)
#pragma unroll
                for (int ks = 0; ks < 2; ++ks)
                    acc[m][n + 2] = __builtin_amdgcn_mfma_f32_16x16x32_bf16(a[m][ks], b1[n][ks], acc[m][n + 2], 0, 0, 0);
        CLOSE_PHASE();

        // ---- P2: t0 Q(m4-7 x n0-1); stage B1(t0+2)
#pragma unroll
        for (int m = 0; m < 4; ++m)
#pragma unroll
            for (int ks = 0; ks < 2; ++ks) a[m][ks] = LDA_(0, m + 4, ks);
        if (pf) STG(gBrow, 32768, gB1, t0 + 2);
        OPEN_PHASE();
#pragma unroll
        for (int m = 0; m < 4; ++m)
#pragma unroll
            for (int n = 0; n < 2; ++n)
#pragma unroll
                for (int ks = 0; ks < 2; ++ks)
                    acc[m + 4][n] = __builtin_amdgcn_mfma_f32_16x16x32_bf16(a[m][ks], b0[n][ks], acc[m + 4][n], 0, 0, 0);
        CLOSE_PHASE();

        // ---- P3: t0 Q(m4-7 x n2-3); stage A2(t0+2); vmcnt -> t1 complete
        if (pf) STG(gArow, 0, gA2, t0 + 2);
        __builtin_amdgcn_s_barrier();
        __builtin_amdgcn_sched_barrier(0);
        __builtin_amdgcn_s_setprio(1);
#pragma unroll
        for (int m = 0; m < 4; ++m)
#pragma unroll
            for (int n = 0; n < 2; ++n)
#pragma unroll
                for (int ks = 0; ks < 2; ++ks)
                    acc[m + 4][n + 2] = __builtin_amdgcn_mfma_f32_16x16x32_bf16(a[m][ks], b1[n][ks], acc[m + 4][n + 2], 0, 0, 0);
        __builtin_amdgcn_s_setprio(0);
        __builtin_amdgcn_sched_barrier(0);
        if (pf) asm volatile("s_waitcnt vmcnt(6)" ::: "memory");
        else    asm volatile("s_waitcnt vmcnt(0)" ::: "memory");
        __builtin_amdgcn_s_barrier();

        // ---- P4: t1 Q(m0-3 x n0-1); stage B2(t0+2)
#pragma unroll
        for (int m = 0; m < 4; ++m)
#pragma unroll
            for (int ks = 0; ks < 2; ++ks) a[m][ks] = LDA_(1, m, ks);
#pragma unroll
        for (int n = 0; n < 2; ++n)
#pragma unroll
            for (int ks = 0; ks < 2; ++ks) b0[n][ks] = LDB_(1, n, ks);
        if (pf) STG(gBrow, 32768, gB2, t0 + 2);
        OPEN_PHASE();
#pragma unroll
        for (int m = 0; m < 4; ++m)
#pragma unroll
            for (int n = 0; n < 2; ++n)
#pragma unroll
                for (int ks = 0; ks < 2; ++ks)
                    acc[m][n] = __builtin_amdgcn_mfma_f32_16x16x32_bf16(a[m][ks], b0[n][ks], acc[m][n], 0, 0, 0);
        CLOSE_PHASE();

        // ---- P5: t1 Q(m0-3 x n2-3); stage A1(t1+2)
#pragma unroll
        for (int n = 0; n < 2; ++n)
#pragma unroll
            for (int ks = 0; ks < 2; ++ks) b1[n][ks] = LDB_(1, n + 2, ks);
        if (pf) STG(gArow, 0, gA1, t1 + 2);
        OPEN_PHASE();
#pragma unroll
        for (int m = 0; m < 4; ++m)
#pragma unroll
            for (int n = 0; n < 2; ++n)
#pragma unroll
                for (int ks = 0; ks < 2; ++ks)
                    acc[m][n + 2] = __builtin_amdgcn_mfma_f32_16x16x32_bf16(a[m][ks], b1[n][ks], acc[m][n + 2], 0, 0, 0);
        CLOSE_PHASE();

        // ---- P6: t1 Q(m4-7 x n0-1); stage B1(t1+2)
#pragma unroll
        for (int m = 0; m < 4; ++m)
#pragma unroll
            for (int ks = 0; ks < 2; ++ks) a[m][ks] = LDA_(1, m + 4, ks);
        if (pf) STG(gBrow, 32768, gB1, t1 + 2);
        OPEN_PHASE();
#pragma unroll
        for (int m = 0; m < 4; ++m)
#pragma unroll
            for (int n = 0; n < 2; ++n)
#pragma unroll
                for (int ks = 0; ks < 2; ++ks)
                    acc[m + 4][n] = __builtin_amdgcn_mfma_f32_16x16x32_bf16(a[m][ks], b0[n][ks], acc[m + 4][n], 0, 0, 0);
        CLOSE_PHASE();

        // ---- P7: t1 Q(m4-7 x n2-3); stage A2(t1+2); vmcnt -> t0+2 complete
        if (pf) STG(gArow, 0, gA2, t1 + 2);
        __builtin_amdgcn_s_barrier();
        __builtin_amdgcn_sched_barrier(0);
        __builtin_amdgcn_s_setprio(1);
#pragma unroll
        for (int m = 0; m < 4; ++m)
#pragma unroll
            for (int n = 0; n < 2; ++n)
#pragma unroll
                for (int ks = 0; ks < 2; ++ks)
                    acc[m + 4][n + 2] = __builtin_amdgcn_mfma_f32_16x16x32_bf16(a[m][ks], b1[n][ks], acc[m + 4][n + 2], 0, 0, 0);
        __builtin_amdgcn_s_setprio(0);
        __builtin_amdgcn_sched_barrier(0);
        if (pf) {
            asm volatile("s_waitcnt vmcnt(6)" ::: "memory");
            __builtin_amdgcn_s_barrier();
        }
    }
#undef OPEN_PHASE
#undef CLOSE_PHASE

    // ---- epilogue (16x16 C/D layout: col=lane&15, row=(lane>>4)*4+reg)
    const int region = (int)(bcol >> 11);            // 0=q, 1=k, 2=v (uniform/block)
#pragma unroll
    for (int m = 0; m < 8; ++m) {
        const size_t row0 = brow + wm * 128 + m * 16 + lg * 4;
#pragma unroll
        for (int n = 0; n < 4; ++n) {
            const size_t col = bcol + wn * 64 + n * 16 + lr;
            const float bv = bias[col];
            if (MODE == 0) {
#pragma unroll
                for (int r = 0; r < 4; ++r)
                    ((float*)Cout)[(row0 + r) * N + col] = acc[m][n][r] + bv;
            } else if (region == 2) {
                // v: bf16 into qkv (stride N=6144), layout unchanged for attn
#pragma unroll
                for (int r = 0; r < 4; ++r)
                    ((u16*)Cout)[(row0 + r) * N + col] = f2bf(acc[m][n][r] + bv);
            } else {
                // q/k: fused RoPE, head-major write. Lane lr^1 holds col^1.
                u16* hb = region ? kb : qb;
                const int d  = (int)(col & 127);
                const int i2 = d >> 1;
                const int h  = (int)((col & 2047) >> 7);
#pragma unroll
                for (int r = 0; r < 4; ++r) {
                    const float v  = acc[m][n][r] + bv;
                    const float pv = __shfl_xor(v, 1);
                    const int row = (int)(row0 + r);
                    const int s = row & 2047, bb = row >> 11;
                    const float c  = fcos[s * 64 + i2];
                    const float sn = fsin[s * 64 + i2];
                    const float o = (d & 1) ? (pv * sn + v * c) : (v * c - pv * sn);
                    hb[((size_t)((bb * 16 + h) * 2048 + s)) * 128 + d] = f2bf(o);
                }
            }
        }
    }
}

// ------------------------------------------------- causal flash attention
// Swapped QK^T (mfma(K,Q)): lane holds 16 P-values of ONE q-row (col=lane&15)
// -> row max/sum are in-lane + 2 butterflies. Counted vmcnt, raw barriers,
// paired q-tiles (x,15-x), XCD-local mapping.
struct VtRegs { uint4v v0, v1, v2, v3; };

__device__ __forceinline__ void attn_stage_k(const u16* kp, int kbase, u16* dstBase,
                                             int w, int lr, int lg) {
#pragma unroll
    for (int c = 0; c < 4; ++c) {
        const int row = w * 16 + c * 4 + lg;
        const int sslot = lr ^ (4 * (c & 1) + lg);           // inverse swizzle on source
        const u16* gsrc = kp + (size_t)(kbase + row) * 128 + sslot * 8;
        __builtin_amdgcn_global_load_lds(AS1(gsrc), AS3(dstBase + (w * 16 + c * 4) * 128), 16, 0, 0);
    }
}

__device__ __forceinline__ VtRegs attn_load_v(const u16* vp, int kbase, int tid) {
    const int rg = tid >> 4, cg = tid & 15;
    const u16* gv = vp + (size_t)(kbase + rg * 4) * 6144 + cg * 8;
    VtRegs r;
    r.v0 = *(const uint4v*)gv;
    r.v1 = *(const uint4v*)(gv + 6144);
    r.v2 = *(const uint4v*)(gv + 2 * 6144);
    r.v3 = *(const uint4v*)(gv + 3 * 6144);
    return r;
}

__device__ __forceinline__ void attn_write_v(u16 (*Vt)[64], const VtRegs& r, int tid) {
    const int rg = tid >> 4, cg = tid & 15;
    const u16* u0 = (const u16*)&r.v0;
    const u16* u1 = (const u16*)&r.v1;
    const u16* u2 = (const u16*)&r.v2;
    const u16* u3 = (const u16*)&r.v3;
    const int sb = rg >> 1, hf = (rg & 1) * 4;
#pragma unroll
    for (int cc = 0; cc < 8; ++cc) {
        const int row = cg * 8 + cc;                          // hd index
        const int col = ((sb ^ ((cg ^ cc) & 7)) << 3) + hf;   // swizzled seq slot
        ushort4v pk = {u0[cc], u1[cc], u2[cc], u3[cc]};
        *(ushort4v*)&Vt[row][col] = pk;
    }
}

__device__ __forceinline__ void attn_qtile(int qt, const u16* qp, const u16* kp,
                                           const u16* vp, u16* yp,
                                           u16 (*Ks)[64][128], u16 (*Vt)[64],
                                           u16 (*Psw)[72],
                                           int w, int lr, int lg, int tid) {
    const int qw = qt * 128 + w * 32;
    const int l = tid & 63;

    bf16x8 qf[2][4];
#pragma unroll
    for (int i = 0; i < 2; ++i)
#pragma unroll
        for (int ks = 0; ks < 4; ++ks)
            qf[i][ks] = *(const bf16x8*)(qp + (size_t)(qw + i * 16 + lr) * 128 + ks * 32 + lg * 8);

    f32x4 acc[2][8];
#pragma unroll
    for (int i = 0; i < 2; ++i)
#pragma unroll
        for (int j = 0; j < 8; ++j) acc[i][j] = (f32x4){0.f, 0.f, 0.f, 0.f};
    float mrow[2] = {-1e30f, -1e30f}, lrow[2] = {0.f, 0.f};   // for q-row = mt*16+lr

    const float scale = 0.08838834764831845f;   // 1/sqrt(128)
    const int nkt = 2 * qt + 2;

    // ---- prologue: V loads first, then K stage (vmcnt(4) leaves K in flight)
    VtRegs vr = attn_load_v(vp, 0, tid);
    attn_stage_k(kp, 0, &Ks[0][0][0], w, lr, lg);
    attn_write_v(Vt, vr, tid);
    __syncthreads();

    int cur = 0;
    for (int kt = 0; kt < nkt; ++kt) {
        const int kbase = kt * 64;
        const bool pf = (kt + 1 < nkt);
        if (pf) {                       // V loads BEFORE K stage (oldest-first drain)
            vr = attn_load_v(vp, kbase + 64, tid);
            attn_stage_k(kp, kbase + 64, &Ks[cur ^ 1][0][0], w, lr, lg);
        }

        if (kbase <= qw + 31) {
            // ---- S^T = K Q^T (swapped operands): lane holds q=mt*16+lr (col),
            //      kv = nt*16 + lg*4 + r (row) -> reduction axis is in-lane!
            f32x4 st[2][4];
#pragma unroll
            for (int i = 0; i < 2; ++i)
#pragma unroll
                for (int j = 0; j < 4; ++j) st[i][j] = (f32x4){0.f, 0.f, 0.f, 0.f};
#pragma unroll
            for (int nt = 0; nt < 4; ++nt) {
#pragma unroll
                for (int ks = 0; ks < 4; ++ks) {
                    const int slot = (ks * 4 + lg) ^ (lr & 7);
                    bf16x8 kf = *(const bf16x8*)&Ks[cur][nt * 16 + lr][slot * 8];
#pragma unroll
                    for (int mt = 0; mt < 2; ++mt)
                        st[mt][nt] = __builtin_amdgcn_mfma_f32_16x16x32_bf16(kf, qf[mt][ks], st[mt][nt], 0, 0, 0);
                }
            }
            // ---- scale + causal mask (ki rows, qi cols)
            const bool pm = (kbase + 63 > qw);
#pragma unroll
            for (int mt = 0; mt < 2; ++mt)
#pragma unroll
                for (int nt = 0; nt < 4; ++nt)
#pragma unroll
                    for (int r = 0; r < 4; ++r) {
                        float v = st[mt][nt][r] * scale;
                        if (pm) {
                            const int qi = qw + mt * 16 + lr;
                            const int ki = kbase + nt * 16 + lg * 4 + r;
                            if (ki > qi) v = -1e30f;
                        }
                        st[mt][nt][r] = v;
                    }
            // ---- row max: 15 in-lane fmax + 2 butterflies across lg copies
            float rm[2], fac[2];
#pragma unroll
            for (int mt = 0; mt < 2; ++mt) {
                float m0 = st[mt][0][0];
#pragma unroll
                for (int nt = 0; nt < 4; ++nt)
#pragma unroll
                    for (int r = 0; r < 4; ++r) m0 = fmaxf(m0, st[mt][nt][r]);
                m0 = fmaxf(m0, __shfl_xor(m0, 16));
                m0 = fmaxf(m0, __shfl_xor(m0, 32));
                rm[mt] = m0;
                const float mn = fmaxf(mrow[mt], m0);
                fac[mt] = __expf(mrow[mt] - mn);
                mrow[mt] = mn;
                lrow[mt] *= fac[mt];
            }
            // ---- redistribute fac to acc layout (acc q-row = lg*4+r)
            float facr[2][4];
#pragma unroll
            for (int mt = 0; mt < 2; ++mt)
#pragma unroll
                for (int r = 0; r < 4; ++r)
                    facr[mt][r] = __shfl(fac[mt], (l & 48) | (lg * 4 + r));
#pragma unroll
            for (int mt = 0; mt < 2; ++mt)
#pragma unroll
                for (int nt = 0; nt < 8; ++nt)
#pragma unroll
                    for (int r = 0; r < 4; ++r) acc[mt][nt][r] *= facr[mt][r];
            // ---- P = exp(S - m): in-lane sum + 2 butterflies
#pragma unroll
            for (int mt = 0; mt < 2; ++mt) {
                float rs = 0.f;
#pragma unroll
                for (int nt = 0; nt < 4; ++nt)
#pragma unroll
                    for (int r = 0; r < 4; ++r) {
                        const float p = __expf(st[mt][nt][r] - mrow[mt]);
                        st[mt][nt][r] = p;
                        rs += p;
                    }
                rs += __shfl_xor(rs, 16);
                rs += __shfl_xor(rs, 32);
                lrow[mt] += rs;
            }
            // ---- P -> LDS, packed b32 (row = q, col = kv)
#pragma unroll
            for (int mt = 0; mt < 2; ++mt)
#pragma unroll
                for (int nt = 0; nt < 4; ++nt) {
                    const u32 p01 = (u32)f2bf(st[mt][nt][0]) | ((u32)f2bf(st[mt][nt][1]) << 16);
                    const u32 p23 = (u32)f2bf(st[mt][nt][2]) | ((u32)f2bf(st[mt][nt][3]) << 16);
                    u16* dst = &Psw[mt * 16 + lr][nt * 16 + lg * 4];
                    *(u32*)dst = p01;
                    *(u32*)(dst + 2) = p23;
                }
            // ---- PV
#pragma unroll
            for (int k2 = 0; k2 < 2; ++k2) {
                bf16x8 pa[2];
                pa[0] = *(const bf16x8*)&Psw[lr][k2 * 32 + lg * 8];
                pa[1] = *(const bf16x8*)&Psw[16 + lr][k2 * 32 + lg * 8];
#pragma unroll
                for (int nt = 0; nt < 8; ++nt) {
                    const int f = ((nt * 2 + (lr >> 3)) ^ lr) & 7;
                    const int slot = (k2 * 4 + lg) ^ f;
                    bf16x8 vb = *(const bf16x8*)&Vt[nt * 16 + lr][slot * 8];
#pragma unroll
                    for (int mt = 0; mt < 2; ++mt)
                        acc[mt][nt] = __builtin_amdgcn_mfma_f32_16x16x32_bf16(pa[mt], vb, acc[mt][nt], 0, 0, 0);
                }
            }
        }

        __builtin_amdgcn_s_barrier();          // all waves done reading Ks[cur]/Vt
        __builtin_amdgcn_sched_barrier(0);
        if (pf) {
            asm volatile("s_waitcnt vmcnt(4)" ::: "memory");   // V landed, K still flying
            attn_write_v(Vt, vr, tid);
            asm volatile("s_waitcnt vmcnt(0) lgkmcnt(0)" ::: "memory"); // K in LDS, V writes done
        } else {
            asm volatile("s_waitcnt vmcnt(0) lgkmcnt(0)" ::: "memory");
        }
        __builtin_amdgcn_s_barrier();
        __builtin_amdgcn_sched_barrier(0);
        cur ^= 1;
    }

    // ---- epilogue: y = acc / l (lrow held at lane lr = q-row; redistribute)
#pragma unroll
    for (int mt = 0; mt < 2; ++mt)
#pragma unroll
        for (int r = 0; r < 4; ++r) {
            const float lsum = __shfl(lrow[mt], (l & 48) | (lg * 4 + r));
            const float inv = 1.f / lsum;
            const size_t row = qw + mt * 16 + lg * 4 + r;
#pragma unroll
            for (int nt = 0; nt < 8; ++nt)
                yp[row * 2048 + nt * 16 + lr] = f2bf(acc[mt][nt][r] * inv);
        }
}

__global__ __launch_bounds__(256, 2) void k_attn(const u16* __restrict__ qb,
                                                 const u16* __restrict__ kb,
                                                 const u16* __restrict__ qkv,
                                                 u16* __restrict__ yb) {
    __shared__ u16 Ks[2][64][128];   // double-buffered, swizzled 16B slots
    __shared__ u16 Vt[128][64];      // V^T, swizzled
    __shared__ u16 Ps[4][32][72];    // per-wave P, padded

    const int gid = blockIdx.x;
    const int x = gid >> 6;          // pair index 0..7 -> q-tiles (x, 15-x)
    const int g = gid & 63;          // (b,h) group; gid%8 == g%8 -> same XCD
    const int h = g & 15, b = g >> 4;
    const int tid = threadIdx.x;
    const int w = tid >> 6, l = tid & 63;
    const int lr = l & 15, lg = l >> 4;

    const u16* qp = qb + (size_t)((b * 16 + h) * 2048) * 128;
    const u16* kp = kb + (size_t)((b * 16 + h) * 2048) * 128;
    const u16* vp = qkv + (size_t)(b * 2048) * 6144 + 4096 + h * 128;
    u16* yp = yb + (size_t)(b * 2048) * 2048 + h * 128;

    attn_qtile(x,      qp, kp, vp, yp, Ks, Vt, Ps[w], w, lr, lg, tid);
    attn_qtile(15 - x, qp, kp, vp, yp, Ks, Vt, Ps[w], w, lr, lg, tid);
}

// --------------------------------------------------------------------------
extern "C" void kernel_launch(void* const* d_in, const int* in_sizes, int n_in,
                              void* d_out, int out_size, void* d_ws, size_t ws_size,
                              hipStream_t stream) {
    const float* x    = (const float*)d_in[0];
    const float* fcos = (const float*)d_in[1];
    const float* fsin = (const float*)d_in[2];
    const float* Wqkv = (const float*)d_in[3];
    const float* bqkv = (const float*)d_in[4];
    const float* Wout = (const float*)d_in[5];
    const float* bout = (const float*)d_in[6];
    float* out = (float*)d_out;

    if (ws_size < 234881024u) return;   // need 224 MB scratch

    char* ws = (char*)d_ws;
    u16* x_bf  = (u16*)(ws);                 // 32 MB  (aliased later by yb)
    u16* wqkvT = (u16*)(ws + 33554432);      // 24 MB
    u16* woutT = (u16*)(ws + 58720256);      //  8 MB
    u16* qkv   = (u16*)(ws + 67108864);      // 96 MB (v region used; q/k unused)
    u16* qb    = (u16*)(ws + 167772160);     // 32 MB (rope'd q, head-major)
    u16* kb    = (u16*)(ws + 201326592);     // 32 MB (rope'd k, head-major)
    u16* yb    = x_bf;                       // alias: x_bf dead after GEMM1

    k_cvt_bf16<<<8192, 256, 0, stream>>>(x, x_bf, 2097152);
    k_transpose_bf16<<<dim3(192, 64), 256, 0, stream>>>(Wqkv, wqkvT, 2048, 6144);
    k_transpose_bf16<<<dim3(64, 64), 256, 0, stream>>>(Wout, woutT, 2048, 2048);
    k_gemm256<2><<<dim3(32, 24), 512, 0, stream>>>(x_bf, wqkvT, bqkv, qkv,
                                                   8192, 6144, 2048,
                                                   fcos, fsin, qb, kb);
    k_attn<<<512, 256, 0, stream>>>(qb, kb, qkv, yb);
    k_gemm256<0><<<dim3(32, 8), 512, 0, stream>>>(yb, woutT, bout, out,
                                                  8192, 2048, 2048,
                                                  nullptr, nullptr, nullptr, nullptr);
}